// Round 8
// baseline (59.013 us; speedup 1.0000x reference)
//
#include <hip/hip_runtime.h>

// Problem dims (fixed by reference setup_inputs)
constexpr int B = 4, P = 8, H = 32, W = 32, D = 32, C = 16;

// Output tile per block and LDS staging capacity (f16, 16ch = 32 B/voxel)
constexpr int TI = 8, TJ = 8, TK = 8;
constexpr int TILE_VOX = TI * TJ * TK;    // 512
constexpr int CAP = 2048;                 // staged input voxels -> 64 KB LDS

using f32x4 = __attribute__((ext_vector_type(4))) float;
using f16x4 = __attribute__((ext_vector_type(4))) _Float16;
using f16x8 = __attribute__((ext_vector_type(8))) _Float16;

__global__ __launch_bounds__(256) void resample_tile(
    const float* __restrict__ fmap,    // [B,P,H,W,D,C] f32
    const float* __restrict__ theta,   // [B,P,3,4]
    float* __restrict__ out)           // [B,P,H,W,D,C] f32
{
    extern __shared__ _Float16 sm[];   // CAP * 16 halfs = 64 KB

    // grid 2048 = 32 bp-slices x 64 tiles (4x4x4 of 8x8x8).
    // XCD swizzle (bijective, 2048%8==0): each XCD walks consecutive tiles
    // of ~4 bp slices -> slice (2 MB f32) stays L2-resident for halo re-reads.
    const int orig = blockIdx.x;
    const int virt = (orig & 7) * 256 + (orig >> 3);
    const int bp = virt >> 6;                    // block-uniform
    const int t6 = virt & 63;
    const int i0 = (t6 >> 4) * TI;
    const int j0 = ((t6 >> 2) & 3) * TJ;
    const int k0 = (t6 & 3) * TK;

    const float4* th4 = (const float4*)(theta + bp * 12);
    const float4 t0 = th4[0];   // -> y
    const float4 t1 = th4[1];   // -> x
    const float4 t2 = th4[2];   // -> z

    // ---- dynamic input bbox from tile corners (affine -> separable extents)
    const float fi0 = (float)i0, fj0 = (float)j0, fk0 = (float)k0;
    const float pyb = fmaf(t0.x, fi0, fmaf(t0.y, fj0, fmaf(t0.z, fk0, t0.w))) + 2.0f;
    const float pxb = fmaf(t1.x, fi0, fmaf(t1.y, fj0, fmaf(t1.z, fk0, t1.w))) + 2.0f;
    const float pzb = fmaf(t2.x, fi0, fmaf(t2.y, fj0, fmaf(t2.z, fk0, t2.w))) + 2.0f;

    const float eyi = t0.x * (TI - 1), eyj = t0.y * (TJ - 1), eyk = t0.z * (TK - 1);
    const float exi = t1.x * (TI - 1), exj = t1.y * (TJ - 1), exk = t1.z * (TK - 1);
    const float ezi = t2.x * (TI - 1), ezj = t2.y * (TJ - 1), ezk = t2.z * (TK - 1);

    const float pymin = pyb + fminf(eyi, 0.f) + fminf(eyj, 0.f) + fminf(eyk, 0.f);
    const float pymax = pyb + fmaxf(eyi, 0.f) + fmaxf(eyj, 0.f) + fmaxf(eyk, 0.f);
    const float pxmin = pxb + fminf(exi, 0.f) + fminf(exj, 0.f) + fminf(exk, 0.f);
    const float pxmax = pxb + fmaxf(exi, 0.f) + fmaxf(exj, 0.f) + fmaxf(exk, 0.f);
    const float pzmin = pzb + fminf(ezi, 0.f) + fminf(ezj, 0.f) + fminf(ezk, 0.f);
    const float pzmax = pzb + fmaxf(ezi, 0.f) + fmaxf(ezj, 0.f) + fmaxf(ezk, 0.f);

    // tap range per axis (clamped unpadded indices actually gathered)
    const int tylo = max(0, min((int)fminf(fmaxf(floorf(pymin), 0.f), 34.f) - 2, 31));
    int       tyhi = min(31, (int)fminf(fmaxf(floorf(pymax), 0.f), 34.f) - 1);
    tyhi = max(tyhi, tylo);
    const int txlo = max(0, min((int)fminf(fmaxf(floorf(pxmin), 0.f), 34.f) - 2, 31));
    int       txhi = min(31, (int)fminf(fmaxf(floorf(pxmax), 0.f), 34.f) - 1);
    txhi = max(txhi, txlo);
    const int tzlo = max(0, min((int)fminf(fmaxf(floorf(pzmin), 0.f), 34.f) - 2, 31));
    int       tzhi = min(31, (int)fminf(fmaxf(floorf(pzmax), 0.f), 34.f) - 1);
    tzhi = max(tzhi, tzlo);

    const int dy = tyhi - tylo + 1;
    const int dx = txhi - txlo + 1;
    const int dz = tzhi - tzlo + 1;
    const int vol = dy * dx * dz;
    const bool fast = (vol <= CAP);              // block-uniform

    const float* slice = fmap + bp * (H * W * D * C);

    // ---- stage bbox into LDS as f16 (dense, contiguous rows along z)
    if (fast) {
        const int wv = threadIdx.x >> 6;         // 4 waves: wave per row
        const int ln = threadIdx.x & 63;
        const int rowch = dz * 4;                // 16B chunks per row
        int ry = 0, rx = wv;
        while (rx >= dx) { rx -= dx; ++ry; }
        while (ry < dy) {
            const float* g = slice + ((tylo + ry) * W + (txlo + rx)) * (D * C)
                                   + tzlo * C;
            _Float16* l = sm + ((ry * dx + rx) * dz) * 16;
            for (int cz = ln; cz < rowch; cz += 64) {
                const f32x4 v = *(const f32x4*)(g + cz * 4);
                f16x4 h;
                h[0] = (_Float16)v[0]; h[1] = (_Float16)v[1];
                h[2] = (_Float16)v[2]; h[3] = (_Float16)v[3];
                *(f16x4*)(l + cz * 4) = h;       // 8 B LDS write
            }
            rx += 4;
            while (rx >= dx) { rx -= dx; ++ry; }
        }
    }
    __syncthreads();

    // ---- gather: each thread does 2 voxels, all 16 channels
    for (int v = threadIdx.x; v < TILE_VOX; v += 256) {
        const int li = v >> 6;
        const int lj = (v >> 3) & 7;
        const int lk = v & 7;
        const float fi = (float)(i0 + li), fj = (float)(j0 + lj), fk = (float)(k0 + lk);

        const float py = fmaf(t0.x, fi, fmaf(t0.y, fj, fmaf(t0.z, fk, t0.w))) + 2.0f;
        const float px = fmaf(t1.x, fi, fmaf(t1.y, fj, fmaf(t1.z, fk, t1.w))) + 2.0f;
        const float pz = fmaf(t2.x, fi, fmaf(t2.y, fj, fmaf(t2.z, fk, t2.w))) + 2.0f;

        // ref: ?0 = clip(floor(?),0,34); ?d = ? - ?0 (NOT re-clamped)
        const float fy0 = fminf(fmaxf(floorf(py), 0.f), 34.f);
        const float fx0 = fminf(fmaxf(floorf(px), 0.f), 34.f);
        const float fz0 = fminf(fmaxf(floorf(pz), 0.f), 34.f);
        const float yd = py - fy0, xd = px - fx0, zd = pz - fz0;
        const int ty0 = (int)fy0 - 2, tx0 = (int)fx0 - 2, tz0 = (int)fz0 - 2;

        // branchless pad: OOB tap -> weight 0 + clamped-safe index
        float wy[2], wx[2], wz[2];
        int   iy[2], ix[2], iz[2];
        wy[0] = ((unsigned)ty0       < (unsigned)H) ? (1.0f - yd) : 0.0f;
        wy[1] = ((unsigned)(ty0 + 1) < (unsigned)H) ? yd          : 0.0f;
        wx[0] = ((unsigned)tx0       < (unsigned)W) ? (1.0f - xd) : 0.0f;
        wx[1] = ((unsigned)(tx0 + 1) < (unsigned)W) ? xd          : 0.0f;
        wz[0] = ((unsigned)tz0       < (unsigned)D) ? (1.0f - zd) : 0.0f;
        wz[1] = ((unsigned)(tz0 + 1) < (unsigned)D) ? zd          : 0.0f;
        iy[0] = min(max(ty0, 0), H - 1);  iy[1] = min(max(ty0 + 1, 0), H - 1);
        ix[0] = min(max(tx0, 0), W - 1);  ix[1] = min(max(tx0 + 1, 0), W - 1);
        iz[0] = min(max(tz0, 0), D - 1);  iz[1] = min(max(tz0 + 1, 0), D - 1);

        f32x4 r0, r1, r2, r3;

        if (fast) {
            // LDS-local coords, clamped into bbox (guards fp-rounding edges;
            // affected taps have ~1e-6 weight)
            int ly[2], lx[2], lz[2];
            ly[0] = min(max(iy[0] - tylo, 0), dy - 1);
            ly[1] = min(max(iy[1] - tylo, 0), dy - 1);
            lx[0] = min(max(ix[0] - txlo, 0), dx - 1);
            lx[1] = min(max(ix[1] - txlo, 0), dx - 1);
            lz[0] = min(max(iz[0] - tzlo, 0), dz - 1);
            lz[1] = min(max(iz[1] - tzlo, 0), dz - 1);

            // two 4-deep f16 chains (corners 0-3 / 4-7) combined in f32
            f16x8 aA0 = 0, aA1 = 0, aB0 = 0, aB1 = 0;
            #pragma unroll
            for (int a = 0; a < 2; ++a)
                #pragma unroll
                for (int b2 = 0; b2 < 2; ++b2)
                    #pragma unroll
                    for (int c2 = 0; c2 < 2; ++c2) {
                        const int cn = a * 4 + b2 * 2 + c2;
                        const int vx = ((ly[a] * dx + lx[b2]) * dz + lz[c2]) * 16;
                        const f16x8 lo = *(const f16x8*)(sm + vx);
                        const f16x8 hi = *(const f16x8*)(sm + vx + 8);
                        const _Float16 h = (_Float16)(wy[a] * wx[b2] * wz[c2]);
                        const f16x8 h8 = {h, h, h, h, h, h, h, h};
                        if (cn < 4) { aA0 += h8 * lo; aA1 += h8 * hi; }
                        else        { aB0 += h8 * lo; aB1 += h8 * hi; }
                    }
            #pragma unroll
            for (int c = 0; c < 4; ++c) {
                r0[c] = (float)aA0[c]     + (float)aB0[c];
                r1[c] = (float)aA0[c + 4] + (float)aB0[c + 4];
                r2[c] = (float)aA1[c]     + (float)aB1[c];
                r3[c] = (float)aA1[c + 4] + (float)aB1[c + 4];
            }
        } else {
            // fallback: direct fp32 global gather (rare oversize bbox)
            f32x4 acc[4] = {{0,0,0,0},{0,0,0,0},{0,0,0,0},{0,0,0,0}};
            #pragma unroll
            for (int a = 0; a < 2; ++a)
                #pragma unroll
                for (int b2 = 0; b2 < 2; ++b2)
                    #pragma unroll
                    for (int c2 = 0; c2 < 2; ++c2) {
                        const float wgt = wy[a] * wx[b2] * wz[c2];
                        const float* p = slice +
                            ((iy[a] * W + ix[b2]) * D + iz[c2]) * C;
                        #pragma unroll
                        for (int q = 0; q < 4; ++q)
                            acc[q] += wgt * *(const f32x4*)(p + q * 4);
                    }
            r0 = acc[0]; r1 = acc[1]; r2 = acc[2]; r3 = acc[3];
        }

        // plain cached stores (NT + 64B-stride lanes = round-6 pathology)
        float* op = out + ((bp * H + (i0 + li)) * W + (j0 + lj)) * (D * C)
                        + (k0 + lk) * C;
        *(f32x4*)(op)      = r0;
        *(f32x4*)(op + 4)  = r1;
        *(f32x4*)(op + 8)  = r2;
        *(f32x4*)(op + 12) = r3;
    }
}

extern "C" void kernel_launch(void* const* d_in, const int* in_sizes, int n_in,
                              void* d_out, int out_size, void* d_ws, size_t ws_size,
                              hipStream_t stream) {
    const float* fmap  = (const float*)d_in[0];
    const float* theta = (const float*)d_in[1];
    float* out = (float*)d_out;

    const int grid = (B * P * H * W * D) / TILE_VOX;        // 2048
    const size_t lds = (size_t)CAP * C * sizeof(_Float16);  // 64 KB
    resample_tile<<<grid, 256, lds, stream>>>(fmap, theta, out);
}

// Round 9
// 28.864 us; speedup vs baseline: 2.0445x; 2.0445x over previous
//
#include <hip/hip_runtime.h>

// Problem dims (fixed by reference setup_inputs)
constexpr int B = 4, P = 8, H = 32, W = 32, D = 32, C = 16;

// Output tile per block: 4 x 4 x 8 (k-contiguous) = 128 voxels.
constexpr int TI = 4, TJ = 4, TK = 8;
// LDS staging cap: 960 input voxels * 16ch f16 = 30 KB -> 5 blocks/CU.
constexpr int VOLCAP = 960;

using f32x4 = __attribute__((ext_vector_type(4))) float;
using f16x8 = __attribute__((ext_vector_type(8))) _Float16;

__global__ __launch_bounds__(256) void resample_tile(
    const float* __restrict__ fmap,    // [B,P,H,W,D,C] f32
    const float* __restrict__ theta,   // [B,P,3,4]
    float* __restrict__ out)           // [B,P,H,W,D,C] f32
{
    __shared__ _Float16 sm[VOLCAP * 16];          // 30720 B

    // grid 8192 = 32 bp-slices x 256 tiles (8i x 8j x 4k).
    // XCD swizzle (bijective, 8192%8==0): consecutive tiles of a slice stay
    // on one XCD -> halo re-reads are L2-local.
    const int orig = blockIdx.x;
    const int virt = (orig & 7) * 1024 + (orig >> 3);
    const int bp = virt >> 8;                     // block-uniform
    const int t6 = virt & 255;
    const int i0 = (t6 >> 5) * TI;
    const int j0 = ((t6 >> 2) & 7) * TJ;
    const int k0 = (t6 & 3) * TK;

    const float4* th4 = (const float4*)(theta + bp * 12);
    const float4 t0 = th4[0];   // -> y
    const float4 t1 = th4[1];   // -> x
    const float4 t2 = th4[2];   // -> z

    // ---- exact input bbox from tile corners (affine -> separable extents)
    const float fi0 = (float)i0, fj0 = (float)j0, fk0 = (float)k0;
    const float pyb = fmaf(t0.x, fi0, fmaf(t0.y, fj0, fmaf(t0.z, fk0, t0.w))) + 2.f;
    const float pxb = fmaf(t1.x, fi0, fmaf(t1.y, fj0, fmaf(t1.z, fk0, t1.w))) + 2.f;
    const float pzb = fmaf(t2.x, fi0, fmaf(t2.y, fj0, fmaf(t2.z, fk0, t2.w))) + 2.f;

    const float eyi = t0.x * (TI - 1), eyj = t0.y * (TJ - 1), eyk = t0.z * (TK - 1);
    const float exi = t1.x * (TI - 1), exj = t1.y * (TJ - 1), exk = t1.z * (TK - 1);
    const float ezi = t2.x * (TI - 1), ezj = t2.y * (TJ - 1), ezk = t2.z * (TK - 1);

    const float pymin = pyb + fminf(eyi, 0.f) + fminf(eyj, 0.f) + fminf(eyk, 0.f);
    const float pymax = pyb + fmaxf(eyi, 0.f) + fmaxf(eyj, 0.f) + fmaxf(eyk, 0.f);
    const float pxmin = pxb + fminf(exi, 0.f) + fminf(exj, 0.f) + fminf(exk, 0.f);
    const float pxmax = pxb + fmaxf(exi, 0.f) + fmaxf(exj, 0.f) + fmaxf(exk, 0.f);
    const float pzmin = pzb + fminf(ezi, 0.f) + fminf(ezj, 0.f) + fminf(ezk, 0.f);
    const float pzmax = pzb + fmaxf(ezi, 0.f) + fmaxf(ezj, 0.f) + fmaxf(ezk, 0.f);

    // tap index range per axis (unpadded, clamped)
    const int tylo = max(0, min((int)fminf(fmaxf(floorf(pymin), 0.f), 34.f) - 2, 31));
    int       tyhi = min(31, (int)fminf(fmaxf(floorf(pymax), 0.f), 34.f) - 1);
    tyhi = max(tyhi, tylo);
    const int txlo = max(0, min((int)fminf(fmaxf(floorf(pxmin), 0.f), 34.f) - 2, 31));
    int       txhi = min(31, (int)fminf(fmaxf(floorf(pxmax), 0.f), 34.f) - 1);
    txhi = max(txhi, txlo);
    const int tzlo = max(0, min((int)fminf(fmaxf(floorf(pzmin), 0.f), 34.f) - 2, 31));
    int       tzhi = min(31, (int)fminf(fmaxf(floorf(pzmax), 0.f), 34.f) - 1);
    tzhi = max(tzhi, tzlo);

    const int dy = tyhi - tylo + 1;
    const int dx = txhi - txlo + 1;
    const int dz = tzhi - tzlo + 1;
    const int vol = dy * dx * dz;
    // dims<=20 keeps the 16-bit magic-division exact (n*(d-1) < 65536)
    const bool fast = (vol <= VOLCAP) && (dy <= 20) && (dx <= 20) && (dz <= 20);

    const float* slice = fmap + bp * (H * W * D * C);

    // ---- stage bbox into LDS as f16, flat chunk loop.
    // chunk s = (voxel vf, half hh): 32B global f32 -> 16B LDS f16.
    // consecutive lanes -> consecutive addresses (dense global runs of
    // dz*64B; conflict-free LDS writes).
    if (fast) {
        const unsigned mdz = 0xFFFFu / (unsigned)dz + 1u;   // exact for our ranges
        const unsigned mdx = 0xFFFFu / (unsigned)dx + 1u;
        const int nch = vol * 2;
        for (int s = threadIdx.x; s < nch; s += 256) {
            const int vf = s >> 1, hh = s & 1;
            const int row = (int)(((unsigned)vf * mdz) >> 16);  // vf / dz
            const int zl  = vf - row * dz;
            const int ry  = (int)(((unsigned)row * mdx) >> 16); // row / dx
            const int rx  = row - ry * dx;
            const float* g = slice
                + (((tylo + ry) * W + (txlo + rx)) * D + (tzlo + zl)) * C + hh * 8;
            const f32x4 a = *(const f32x4*)g;
            const f32x4 b = *(const f32x4*)(g + 4);
            f16x8 hv;
            hv[0] = (_Float16)a[0]; hv[1] = (_Float16)a[1];
            hv[2] = (_Float16)a[2]; hv[3] = (_Float16)a[3];
            hv[4] = (_Float16)b[0]; hv[5] = (_Float16)b[1];
            hv[6] = (_Float16)b[2]; hv[7] = (_Float16)b[3];
            *(f16x8*)(sm + vf * 16 + hh * 8) = hv;
        }
    }
    __syncthreads();

    // ---- gather: 2 lanes per voxel (each owns 8 channels) -> LDS corner
    // reads are lane-consecutive 16B; stores are 512B-contiguous runs.
    const int h8 = threadIdx.x & 1;
    const int v  = threadIdx.x >> 1;              // 0..127
    const int lk = v & 7;
    const int lj = (v >> 3) & 3;
    const int li = v >> 5;

    const float fi = (float)(i0 + li), fj = (float)(j0 + lj), fk = (float)(k0 + lk);
    const float py = fmaf(t0.x, fi, fmaf(t0.y, fj, fmaf(t0.z, fk, t0.w))) + 2.f;
    const float px = fmaf(t1.x, fi, fmaf(t1.y, fj, fmaf(t1.z, fk, t1.w))) + 2.f;
    const float pz = fmaf(t2.x, fi, fmaf(t2.y, fj, fmaf(t2.z, fk, t2.w))) + 2.f;

    // ref: ?0 = clip(floor(?),0,34); ?d = ? - ?0 (NOT re-clamped)
    const float fy0 = fminf(fmaxf(floorf(py), 0.f), 34.f);
    const float fx0 = fminf(fmaxf(floorf(px), 0.f), 34.f);
    const float fz0 = fminf(fmaxf(floorf(pz), 0.f), 34.f);
    const float yd = py - fy0, xd = px - fx0, zd = pz - fz0;
    const int ty0 = (int)fy0 - 2, tx0 = (int)fx0 - 2, tz0 = (int)fz0 - 2;

    // branchless pad: OOB tap -> weight 0 + clamped-safe index
    float wy[2], wx[2], wz[2];
    int   iy[2], ix[2], iz[2];
    wy[0] = ((unsigned)ty0       < (unsigned)H) ? (1.0f - yd) : 0.0f;
    wy[1] = ((unsigned)(ty0 + 1) < (unsigned)H) ? yd          : 0.0f;
    wx[0] = ((unsigned)tx0       < (unsigned)W) ? (1.0f - xd) : 0.0f;
    wx[1] = ((unsigned)(tx0 + 1) < (unsigned)W) ? xd          : 0.0f;
    wz[0] = ((unsigned)tz0       < (unsigned)D) ? (1.0f - zd) : 0.0f;
    wz[1] = ((unsigned)(tz0 + 1) < (unsigned)D) ? zd          : 0.0f;
    iy[0] = min(max(ty0, 0), H - 1);  iy[1] = min(max(ty0 + 1, 0), H - 1);
    ix[0] = min(max(tx0, 0), W - 1);  ix[1] = min(max(tx0 + 1, 0), W - 1);
    iz[0] = min(max(tz0, 0), D - 1);  iz[1] = min(max(tz0 + 1, 0), D - 1);

    f32x4 r0, r1;

    if (fast) {
        // LDS-local tap coords; clamp guards fp-rounding edges (the tap that
        // can fall outside the bbox carries ~1e-5 weight — round-8-proven).
        int ly[2], lx[2], lz[2];
        ly[0] = min(max(iy[0] - tylo, 0), dy - 1);
        ly[1] = min(max(iy[1] - tylo, 0), dy - 1);
        lx[0] = min(max(ix[0] - txlo, 0), dx - 1);
        lx[1] = min(max(ix[1] - txlo, 0), dx - 1);
        lz[0] = min(max(iz[0] - tzlo, 0), dz - 1);
        lz[1] = min(max(iz[1] - tzlo, 0), dz - 1);

        // two 4-deep f16 chains (corners 0-3 / 4-7), combined in f32
        // (round-6-proven numerics: absmax stayed 0.015625)
        f16x8 aA = 0, aB = 0;
        #pragma unroll
        for (int a = 0; a < 2; ++a)
            #pragma unroll
            for (int b2 = 0; b2 < 2; ++b2)
                #pragma unroll
                for (int c2 = 0; c2 < 2; ++c2) {
                    const int cn = a * 4 + b2 * 2 + c2;
                    const int vf = (ly[a] * dx + lx[b2]) * dz + lz[c2];
                    const f16x8 d = *(const f16x8*)(sm + vf * 16 + h8 * 8);
                    const _Float16 hw = (_Float16)(wy[a] * wx[b2] * wz[c2]);
                    const f16x8 hv = {hw, hw, hw, hw, hw, hw, hw, hw};
                    if (cn < 4) aA += hv * d; else aB += hv * d;
                }
        r0[0] = (float)aA[0] + (float)aB[0];
        r0[1] = (float)aA[1] + (float)aB[1];
        r0[2] = (float)aA[2] + (float)aB[2];
        r0[3] = (float)aA[3] + (float)aB[3];
        r1[0] = (float)aA[4] + (float)aB[4];
        r1[1] = (float)aA[5] + (float)aB[5];
        r1[2] = (float)aA[6] + (float)aB[6];
        r1[3] = (float)aA[7] + (float)aB[7];
    } else {
        // fallback: direct fp32 global gather (rare oversize bbox)
        const float* gb = slice + h8 * 8;
        f32x4 acc0 = {0,0,0,0}, acc1 = {0,0,0,0};
        #pragma unroll
        for (int a = 0; a < 2; ++a)
            #pragma unroll
            for (int b2 = 0; b2 < 2; ++b2)
                #pragma unroll
                for (int c2 = 0; c2 < 2; ++c2) {
                    const float wgt = wy[a] * wx[b2] * wz[c2];
                    const float* p = gb + ((iy[a] * W + ix[b2]) * D + iz[c2]) * C;
                    acc0 += wgt * *(const f32x4*)p;
                    acc1 += wgt * *(const f32x4*)(p + 4);
                }
        r0 = acc0; r1 = acc1;
    }

    // plain cached stores; lane-contiguous (lane l -> byte offset l*32 within
    // the wave's 2KB segment) -> full-line write-combining.
    float* op = out + (((bp * H + (i0 + li)) * W + (j0 + lj)) * D + (k0 + lk)) * C
                    + h8 * 8;
    *(f32x4*)op       = r0;
    *(f32x4*)(op + 4) = r1;
}

extern "C" void kernel_launch(void* const* d_in, const int* in_sizes, int n_in,
                              void* d_out, int out_size, void* d_ws, size_t ws_size,
                              hipStream_t stream) {
    const float* fmap  = (const float*)d_in[0];
    const float* theta = (const float*)d_in[1];
    float* out = (float*)d_out;

    const int grid = (B * P * H * W * D) / (TI * TJ * TK);   // 8192
    resample_tile<<<grid, 256, 0, stream>>>(fmap, theta, out);
}